// Round 19
// baseline (178.286 us; speedup 1.0000x reference)
//
#include <hip/hip_runtime.h>
#include <hip/hip_bf16.h>

// Problem constants
#define C_   32
#define S_   20
#define V_   8000     // 20^3
#define K3_  125
#define OC_  375      // 3*K3
#define NP_  384      // padded N
#define KK_  4000     // 32*125

// Workspace layout (float offsets). Peak 2.704M floats = 10.82 MB (unchanged).
#define WS_ATTN1T 0                        // fp32 [v][c]          256000
#define WS_XT     256000                   // f16  [v][c]          128000 fl
#define WS_WDWT   384000                   // fp32 [k][c]            4000
#define WS_WSPT   388000                   // fp32 [k][c]           10976
#define WS_WPWT   398976                   // fp32 [c][o]            1024
#define WS_OFFB   400000                   // f16  [v][384]       1536000 fl
#define WS_BPREP  1936000                  // f16 [n][k] 768000 fl (spans to
                                           //   2704000!); dead after gemm
#define WS_XP     1936000                  //   -> reused AFTER gemm: half2
                                           //   [v][c] 256000 fl. R13 ERRATum:
                                           //   xp CANNOT be written pre-gemm —
                                           //   no free 256000-fl region exists.
// Zero page: first 16 floats of ATTN1T region (dead until deform_kernel).
#define WS_ZERO   WS_ATTN1T

typedef __attribute__((ext_vector_type(8))) short bf16x8;
typedef __attribute__((ext_vector_type(4))) float f32x4;
typedef __fp16 h2_t __attribute__((ext_vector_type(2)));   // matches builtins

static __device__ __forceinline__ unsigned short f2h(float f) {
    _Float16 h = (_Float16)f;
    return __builtin_bit_cast(unsigned short, h);
}
static __device__ __forceinline__ float h2f(unsigned short b) {
    return (float)__builtin_bit_cast(_Float16, b);
}
static __device__ __forceinline__ h2_t bch2(unsigned u) {
    return __builtin_bit_cast(h2_t, u);
}
static __device__ __forceinline__ unsigned pkh2(float a, float b) {
#if __has_builtin(__builtin_amdgcn_cvt_pkrtz)
    return __builtin_bit_cast(unsigned, __builtin_amdgcn_cvt_pkrtz(a, b));
#else
    return (unsigned)f2h(a) | ((unsigned)f2h(b) << 16);
#endif
}
static __device__ __forceinline__ float dot2(unsigned xu, unsigned wu, float c) {
#if __has_builtin(__builtin_amdgcn_fdot2)
    return __builtin_amdgcn_fdot2(bch2(xu), bch2(wu), c, false);
#else
    h2_t xh = bch2(xu), wh = bch2(wu);
    return c + (float)xh[0] * (float)wh[0] + (float)xh[1] * (float)wh[1];
#endif
}

// ---------------------------------------------------------------------------
// FUSED PREP (transpose + prep_b + small weights; all outputs DISJOINT —
// xp deliberately NOT produced here, see WS_XP erratum above):
//  blocks 0..124   : 64v x 32c transpose tile -> xt[v][c] f16.
//                    LDS [32][65]: stride 65 = 1 mod 32, conflict-free.
//  blocks 125..508 : prep_b row n = b-125 (coalesced via 16 KB LDS; read
//                    stride 125 = 29 mod 32, conflict-free; n >= 375 zeroed).
//  blocks 509..571 : small weight transposes (wdwT/wspT/wpwT) + zero page.
// All branches independent -> concurrent instead of 3 serialized launches.
// ---------------------------------------------------------------------------
__global__ __launch_bounds__(256) void prep_kernel(
    const float* __restrict__ x,
    const float* __restrict__ w_off,
    const float* __restrict__ w_dw,
    const float* __restrict__ w_sp,
    const float* __restrict__ w_pw,
    unsigned short* __restrict__ xt,
    unsigned short* __restrict__ Bprep,
    float* __restrict__ wdwT,
    float* __restrict__ wspT,
    float* __restrict__ wpwT,
    float* __restrict__ zpage)
{
    __shared__ float sh[KK_];               // 16 KB, shared by both branches
    const int tid = threadIdx.x;
    const int b = blockIdx.x;

    if (b < 125) {
        float (*tile)[65] = (float(*)[65])sh;   // 32 x 65 (2080 fl used)
        const int v0 = b * 64;
        {   // read: 64 consecutive v per c-row (coalesced 256B)
            int vv = tid & 63, cc = tid >> 6;
            #pragma unroll
            for (int p = 0; p < 8; ++p)
                tile[cc + p * 4][vv] = x[(cc + p * 4) * V_ + v0 + vv];
        }
        __syncthreads();
        {   // write xt (coalesced 128B rows)
            int c = tid & 31, vl = tid >> 5;
            #pragma unroll
            for (int p = 0; p < 8; ++p) {
                int v = vl + p * 8;
                xt[(v0 + v) * 32 + c] = f2h(tile[c][v]);
            }
        }
        return;
    }

    int nb = b - 125;
    if (nb < NP_) {
        const bool live = nb < OC_;
        for (int i = tid; i < KK_; i += 256)
            sh[i] = live ? w_off[(size_t)nb * KK_ + i] : 0.f;
        __syncthreads();
        for (int j = tid; j < KK_; j += 256) {
            int tap = j >> 5, c = j & 31;
            Bprep[(size_t)nb * KK_ + j] = f2h(sh[c * K3_ + tap]);
        }
        return;
    }

    int j = (nb - NP_) * 256 + tid;
    if (j < 4000)  { wdwT[j] = w_dw[(j & 31) * K3_ + (j >> 5)]; return; }
    j -= 4000;
    if (j < 10976) { wspT[j] = w_sp[(j & 31) * 343 + (j >> 5)]; return; }
    j -= 10976;
    if (j < 1024)  { wpwT[j] = w_pw[(j & 31) * 32 + (j >> 5)]; return; }
    j -= 1024;
    if (j < 16)    { zpage[j] = 0.f; return; }
}

// ---------------------------------------------------------------------------
// Offset conv as implicit-GEMM MFMA (f16): D[8000][384] = A[8000][4000]*B.
// EXACT R4 STRUCTURE (verified best: ~54-56us, conflicts=0). Tile 64x64,
// BK=64 (2 taps/iter), 4 waves 2x2, wave tile 32x32. 2-phase pipeline,
// global_load_lds staging, double-buffered LDS (32KB), one barrier/K-step.
// LDS XOR-swizzle (T2, both-sides): write side fetches inverse-swizzled
// global chunk (linear LDS dest); read side XORs quad with (lrow>>1)&3.
// Ledger (R5-R8): 128-tile, counted-vmcnt 4-buf, B-in-VGPR, cube scheme
// all regressed (occupancy / barrier-drain / bank-uniformity). Keep R4.
// Writes offbT[v][n] f16 (+bias).
// ---------------------------------------------------------------------------
__global__ __launch_bounds__(256) void gemm_off_kernel(
    const unsigned short* __restrict__ xt,
    const unsigned short* __restrict__ Bprep,
    const float* __restrict__ b_off,
    const float* __restrict__ zpage,
    unsigned short* __restrict__ offbT)
{
    __shared__ unsigned short A_lds[2][2][64 * 32];   // [buf][h][row*32+k]
    __shared__ unsigned short B_lds[2][2][64 * 32];

    const int t    = threadIdx.x;
    const int lane = t & 63;
    const int wave = t >> 6;
    const int wr   = wave >> 1;
    const int wc   = wave & 1;
    const int quad = lane >> 4;
    const int lrow = lane & 15;
    const int M0   = blockIdx.x * 64;
    const int N0   = blockIdx.y * 64;

    const int srow = t >> 2;
    const int soff = ((t & 3) ^ ((t >> 3) & 3)) * 8;   // shorts, swizzled
    const int mg = M0 + srow;
    const int az = mg / 400, arm = mg % 400;
    const int ay = arm / 20, ax = arm % 20;
    const unsigned short* brow = Bprep + (size_t)(N0 + srow) * KK_;
    const unsigned short* zp   = (const unsigned short*)zpage;
    const int ldsoff = wave * 512;          // shorts: wave's 1024B chunk
    const int xorc = (lrow >> 1) & 3;

    f32x4 acc[2][2] = {};

    auto stage = [&](int buf, int tap0) {
        #pragma unroll
        for (int h = 0; h < 2; ++h) {
            int tap = tap0 + h;
            int kz = tap / 25, ky = (tap / 5) % 5, kx = tap % 5;
            int zi = az - 2 + kz, yi = ay - 2 + ky, xi = ax - 2 + kx;
            bool intap = tap < K3_;
            bool ok = intap & ((unsigned)zi < (unsigned)S_)
                            & ((unsigned)yi < (unsigned)S_)
                            & ((unsigned)xi < (unsigned)S_);
            int px = zi * 400 + yi * 20 + xi;
            const unsigned short* ga = ok    ? (xt + px * 32 + soff)    : zp;
            const unsigned short* gb = intap ? (brow + tap * 32 + soff) : zp;
            __builtin_amdgcn_global_load_lds(
                (const __attribute__((address_space(1))) void*)ga,
                (__attribute__((address_space(3))) void*)(&A_lds[buf][h][ldsoff]),
                16, 0, 0);
            __builtin_amdgcn_global_load_lds(
                (const __attribute__((address_space(1))) void*)gb,
                (__attribute__((address_space(3))) void*)(&B_lds[buf][h][ldsoff]),
                16, 0, 0);
        }
    };

    stage(0, 0);
    __syncthreads();

    int cur = 0;
    for (int it = 0; it < 63; ++it) {
        if (it < 62) stage(cur ^ 1, (it + 1) * 2);
        #pragma unroll
        for (int h = 0; h < 2; ++h) {
            bf16x8 af[2], bf[2];
            #pragma unroll
            for (int mi = 0; mi < 2; ++mi)
                af[mi] = *(const bf16x8*)&A_lds[cur][h][(wr * 32 + mi * 16 + lrow) * 32 + (quad ^ xorc) * 8];
            #pragma unroll
            for (int ni = 0; ni < 2; ++ni)
                bf[ni] = *(const bf16x8*)&B_lds[cur][h][(wc * 32 + ni * 16 + lrow) * 32 + (quad ^ xorc) * 8];
            #pragma unroll
            for (int mi = 0; mi < 2; ++mi)
                #pragma unroll
                for (int ni = 0; ni < 2; ++ni)
                    acc[mi][ni] = __builtin_amdgcn_mfma_f32_16x16x32_f16(
                        af[mi], bf[ni], acc[mi][ni], 0, 0, 0);
        }
        __syncthreads();
        cur ^= 1;
    }

    #pragma unroll
    for (int mi = 0; mi < 2; ++mi) {
        #pragma unroll
        for (int ni = 0; ni < 2; ++ni) {
            int n = N0 + wc * 32 + ni * 16 + lrow;
            if (n < OC_) {
                float bias = b_off[n];
                #pragma unroll
                for (int r = 0; r < 4; ++r) {
                    int row = wr * 32 + mi * 16 + quad * 4 + r;
                    offbT[(size_t)(M0 + row) * 384 + n] = f2h(acc[mi][ni][r] + bias);
                }
            }
        }
    }
}

// ---------------------------------------------------------------------------
// xp[v][c] = half2(x[v][c], x[v+1][c]) — makes the (w0,w1) trilinear x-pair
// a single dword load in deform. xp[7999].y = 0 (never used with nonzero wt).
// MUST run after gemm: xp aliases Bprep (R13 erratum — no pre-gemm space).
// ---------------------------------------------------------------------------
__global__ __launch_bounds__(256) void pack_xp_kernel(
    const unsigned short* __restrict__ xt, unsigned* __restrict__ xp)
{
    int i = blockIdx.x * 256 + threadIdx.x;
    if (i >= 256000) return;
    unsigned lo = xt[i];
    unsigned hi = (i < 256000 - 32) ? (unsigned)xt[i + 32] : 0u;
    xp[i] = lo | (hi << 16);
}

// ---------------------------------------------------------------------------
// Deformable depthwise sample, two-phase. R19: TLP-split — VB 8->4, two
// threads per (v,c) output, g = tid>>7 takes taps of parity g (union =
// all 125). Inner body BYTE-IDENTICAL to R14/R17 (chained fdot2, unroll
// 16); partials combine via 1 KB LDS. Waves 4000 -> 8000 (latency-bound
// kernel at ~25% occupancy: residency doubles, per-thread work halves).
// ---------------------------------------------------------------------------
#define VB 4
__global__ __launch_bounds__(256) void deform_kernel(
    const unsigned* __restrict__ xp,
    const float* __restrict__ wdwT,
    const float* __restrict__ b_dw,
    const unsigned short* __restrict__ offbT,
    float* __restrict__ attn1T)
{
    __shared__ unsigned sw[VB * 128 * 8];   // 16 KB, 32B per (v,tap) entry
    __shared__ float s_part[VB][32][2];     // 1 KB partials
    const int tid = threadIdx.x;
    const int Vb = blockIdx.x * VB;

    for (int idx = tid; idx < VB * 128; idx += 256) {
        int vl = idx >> 7, tap = idx & 127;
        if (tap < K3_) {
            int v = Vb + vl;
            int z = v / 400, rm = v % 400;
            int y = rm / 20, xx = rm % 20;
            int kz = tap / 25, ky = (tap / 5) % 5, kx = tap % 5;
            const unsigned short* ob = offbT + v * 384 + 3 * tap;
            float pd = (float)(z - 2 + kz) + h2f(ob[0]);
            float ph = (float)(y - 2 + ky) + h2f(ob[1]);
            float pw = (float)(xx - 2 + kx) + h2f(ob[2]);
            float fd0 = floorf(pd), fh0 = floorf(ph), fw0 = floorf(pw);
            float fd = pd - fd0, fh = ph - fh0, fw = pw - fw0;
            int id = (int)fd0, ih = (int)fh0, iw = (int)fw0;
            int d0 = min(max(id, 0), S_ - 1), d1 = min(max(id + 1, 0), S_ - 1);
            int h0 = min(max(ih, 0), S_ - 1), h1 = min(max(ih + 1, 0), S_ - 1);
            float wd0 = ((unsigned)id       < (unsigned)S_) ? 1.f - fd : 0.f;
            float wd1 = ((unsigned)(id + 1) < (unsigned)S_) ? fd       : 0.f;
            float wh0 = ((unsigned)ih       < (unsigned)S_) ? 1.f - fh : 0.f;
            float wh1 = ((unsigned)(ih + 1) < (unsigned)S_) ? fh       : 0.f;
            float ww0 = ((unsigned)iw       < (unsigned)S_) ? 1.f - fw : 0.f;
            float ww1 = ((unsigned)(iw + 1) < (unsigned)S_) ? fw       : 0.f;
            int px; float wwa, wwb;
            if (iw < 0) { px = 0;             wwa = ww1; wwb = 0.f; }
            else        { px = min(iw, S_-1); wwa = ww0; wwb = ww1; }
            int r00 = d0 * 400 + h0 * 20 + px;
            int r01 = d0 * 400 + h1 * 20 + px;
            int r10 = d1 * 400 + h0 * 20 + px;
            int r11 = d1 * 400 + h1 * 20 + px;
            float w00 = wd0 * wh0, w01 = wd0 * wh1;
            float w10 = wd1 * wh0, w11 = wd1 * wh1;
            unsigned* q = &sw[idx * 8];
            q[0] = pkh2(w00 * wwa, w00 * wwb);
            q[1] = pkh2(w01 * wwa, w01 * wwb);
            q[2] = pkh2(w10 * wwa, w10 * wwb);
            q[3] = pkh2(w11 * wwa, w11 * wwb);
            q[4] = (unsigned)r00 | ((unsigned)r01 << 16);
            q[5] = (unsigned)r10 | ((unsigned)r11 << 16);
        }
    }
    __syncthreads();

    const int c  = tid & 31;
    const int vl = (tid >> 5) & 3;
    const int g  = tid >> 7;
    const unsigned* xpc = xp + c;
    float acc = 0.f;
    #pragma unroll 16
    for (int tap = g; tap < K3_; tap += 2) {
        const unsigned* q = &sw[(vl * 128 + tap) * 8];
        unsigned w00u = q[0], w01u = q[1], w10u = q[2], w11u = q[3];
        unsigned pA = q[4], pB = q[5];
        int p00 = pA & 0xFFFFu, p01 = pA >> 16;
        int p10 = pB & 0xFFFFu, p11 = pB >> 16;
        float s = dot2(xpc[p00 * 32], w00u,
                  dot2(xpc[p01 * 32], w01u,
                  dot2(xpc[p10 * 32], w10u,
                  dot2(xpc[p11 * 32], w11u, 0.f))));
        acc += wdwT[tap * 32 + c] * s;
    }
    s_part[vl][c][g] = acc;
    __syncthreads();
    if (tid < 128)
        attn1T[(Vb + vl) * 32 + c] =
            s_part[vl][c][0] + s_part[vl][c][1] + b_dw[c];
}

// ---------------------------------------------------------------------------
// FUSED: depthwise 7^3 conv (dil 3, pad 9) + pointwise 32x32 + gate.
// R19: TLP-split — 4 voxels/block, two threads per (v,c), g = tid>>7 takes
// kz of parity g within [kz_lo,kz_hi] (union = full range). Inner body
// BYTE-IDENTICAL to R16/R18 (hybrid bounds, unrolled kx). b_sp folded in
// phase B: attn[cc] = s0+s1+b_sp[cc]. Waves 4000 -> 8000.
// ---------------------------------------------------------------------------
__global__ __launch_bounds__(256) void spatial_pw_kernel(
    const float* __restrict__ wspT,
    const float* __restrict__ b_sp,
    const float* __restrict__ attn1T,
    const float* __restrict__ wpwT,
    const float* __restrict__ b_pw,
    const float* __restrict__ x,
    float* __restrict__ out)
{
    __shared__ float s_sp[4][32][2];
    int t = threadIdx.x;
    int c = t & 31;
    int vl = (t >> 5) & 3;
    int g = t >> 7;
    int v = blockIdx.x * 4 + vl;
    int z = v / 400, rm = v % 400;
    int y = rm / 20, xx = rm % 20;

    // Valid ranges: 0 <= q-9+3k <= 19 -> ceil((9-q)/3) <= k <= (28-q)/3.
    int kz_lo = max(0, (11 - z) / 3), kz_hi = min(6, (28 - z) / 3);
    int ky_lo = max(0, (11 - y) / 3), ky_hi = min(6, (28 - y) / 3);

    float acc = 0.f;
    #pragma unroll 1
    for (int kz = kz_lo + g; kz <= kz_hi; kz += 2) {
        int zi = z - 9 + 3 * kz;                 // always in-bounds
        #pragma unroll 2
        for (int ky = ky_lo; ky <= ky_hi; ++ky) {
            int yi = y - 9 + 3 * ky;             // always in-bounds
            int abase = (zi * 400 + yi * 20) * 32 + c;
            int wbase = (kz * 49 + ky * 7) * 32 + c;
            #pragma unroll
            for (int kx = 0; kx < 7; ++kx) {     // full unroll: 7-deep MLP
                int xi = xx - 9 + 3 * kx;
                bool xv = (unsigned)xi < (unsigned)S_;
                int xc2 = min(max(xi, 0), S_ - 1);
                float a = attn1T[abase + xc2 * 32];
                float w = wspT[wbase + kx * 32];
                acc += xv ? a * w : 0.f;
            }
        }
    }
    s_sp[vl][c][g] = acc;
    __syncthreads();

    if (t < 128) {
        const int o = c;
        float acc2 = b_pw[o];
        #pragma unroll
        for (int cc = 0; cc < C_; ++cc)
            acc2 += wpwT[cc * 32 + o] *
                    (s_sp[vl][cc][0] + s_sp[vl][cc][1] + b_sp[cc]);
        out[o * V_ + v] = x[o * V_ + v] * acc2;
    }
}

// ---------------------------------------------------------------------------
extern "C" void kernel_launch(void* const* d_in, const int* in_sizes, int n_in,
                              void* d_out, int out_size, void* d_ws, size_t ws_size,
                              hipStream_t stream)
{
    const float* x     = (const float*)d_in[0];
    const float* w_off = (const float*)d_in[1];
    const float* b_off = (const float*)d_in[2];
    const float* w_dw  = (const float*)d_in[3];
    const float* b_dw  = (const float*)d_in[4];
    const float* w_sp  = (const float*)d_in[5];
    const float* b_sp  = (const float*)d_in[6];
    const float* w_pw  = (const float*)d_in[7];
    const float* b_pw  = (const float*)d_in[8];
    float* ws = (float*)d_ws;
    float* out = (float*)d_out;

    unsigned short* xt    = (unsigned short*)(ws + WS_XT);
    unsigned short* offbT = (unsigned short*)(ws + WS_OFFB);
    unsigned short* Bprep = (unsigned short*)(ws + WS_BPREP);
    unsigned*       xp    = (unsigned*)(ws + WS_XP);

    // 125 tile blocks + 384 prep_b rows + 63 weight-tail blocks = 572
    hipLaunchKernelGGL(prep_kernel, dim3(572), dim3(256), 0, stream,
                       x, w_off, w_dw, w_sp, w_pw,
                       xt, Bprep,
                       ws + WS_WDWT, ws + WS_WSPT, ws + WS_WPWT, ws + WS_ZERO);

    hipLaunchKernelGGL(gemm_off_kernel, dim3(125, 6), dim3(256), 0, stream,
                       xt, Bprep, b_off, ws + WS_ZERO, offbT);

    hipLaunchKernelGGL(pack_xp_kernel, dim3(1000), dim3(256), 0, stream,
                       xt, xp);

    hipLaunchKernelGGL(deform_kernel, dim3(2000), dim3(256), 0, stream,
                       xp, ws + WS_WDWT, b_dw, offbT, ws + WS_ATTN1T);

    hipLaunchKernelGGL(spatial_pw_kernel, dim3(2000), dim3(256), 0, stream,
                       ws + WS_WSPT, b_sp, ws + WS_ATTN1T,
                       ws + WS_WPWT, b_pw, x, out);
}

// Round 20
// 172.823 us; speedup vs baseline: 1.0316x; 1.0316x over previous
//
#include <hip/hip_runtime.h>
#include <hip/hip_bf16.h>

// Problem constants
#define C_   32
#define S_   20
#define V_   8000     // 20^3
#define K3_  125
#define OC_  375      // 3*K3
#define NP_  384      // padded N
#define KK_  4000     // 32*125

// Workspace layout (float offsets). Peak 2.704M floats = 10.82 MB (unchanged).
#define WS_ATTN1T 0                        // fp32 [v][c]          256000
#define WS_XT     256000                   // f16  [v][c]          128000 fl
#define WS_WDWT   384000                   // fp32 [k][c]            4000
#define WS_WSPT   388000                   // fp32 [k][c]           10976
#define WS_WPWT   398976                   // fp32 [c][o]            1024
#define WS_OFFB   400000                   // f16  [v][384]       1536000 fl
#define WS_BPREP  1936000                  // f16 [n][k] 768000 fl (spans to
                                           //   2704000!); dead after gemm
#define WS_XP     1936000                  //   -> reused AFTER gemm: half2
                                           //   [v][c] 256000 fl. R13 ERRATum:
                                           //   xp CANNOT be written pre-gemm —
                                           //   no free 256000-fl region exists.
// Zero page: first 16 floats of ATTN1T region (dead until deform_kernel).
#define WS_ZERO   WS_ATTN1T

typedef __attribute__((ext_vector_type(8))) short bf16x8;
typedef __attribute__((ext_vector_type(4))) float f32x4;
typedef __fp16 h2_t __attribute__((ext_vector_type(2)));   // matches builtins

static __device__ __forceinline__ unsigned short f2h(float f) {
    _Float16 h = (_Float16)f;
    return __builtin_bit_cast(unsigned short, h);
}
static __device__ __forceinline__ float h2f(unsigned short b) {
    return (float)__builtin_bit_cast(_Float16, b);
}
static __device__ __forceinline__ h2_t bch2(unsigned u) {
    return __builtin_bit_cast(h2_t, u);
}
static __device__ __forceinline__ unsigned pkh2(float a, float b) {
#if __has_builtin(__builtin_amdgcn_cvt_pkrtz)
    return __builtin_bit_cast(unsigned, __builtin_amdgcn_cvt_pkrtz(a, b));
#else
    return (unsigned)f2h(a) | ((unsigned)f2h(b) << 16);
#endif
}
static __device__ __forceinline__ float dot2(unsigned xu, unsigned wu, float c) {
#if __has_builtin(__builtin_amdgcn_fdot2)
    return __builtin_amdgcn_fdot2(bch2(xu), bch2(wu), c, false);
#else
    h2_t xh = bch2(xu), wh = bch2(wu);
    return c + (float)xh[0] * (float)wh[0] + (float)xh[1] * (float)wh[1];
#endif
}

// ---------------------------------------------------------------------------
// FUSED PREP (transpose + prep_b + small weights; all outputs DISJOINT —
// xp deliberately NOT produced here, see WS_XP erratum above):
//  blocks 0..124   : 64v x 32c transpose tile -> xt[v][c] f16.
//                    LDS [32][65]: stride 65 = 1 mod 32, conflict-free.
//  blocks 125..508 : prep_b row n = b-125 (coalesced via 16 KB LDS; read
//                    stride 125 = 29 mod 32, conflict-free; n >= 375 zeroed).
//  blocks 509..571 : small weight transposes (wdwT/wspT/wpwT) + zero page.
// All branches independent -> concurrent instead of 3 serialized launches.
// ---------------------------------------------------------------------------
__global__ __launch_bounds__(256) void prep_kernel(
    const float* __restrict__ x,
    const float* __restrict__ w_off,
    const float* __restrict__ w_dw,
    const float* __restrict__ w_sp,
    const float* __restrict__ w_pw,
    unsigned short* __restrict__ xt,
    unsigned short* __restrict__ Bprep,
    float* __restrict__ wdwT,
    float* __restrict__ wspT,
    float* __restrict__ wpwT,
    float* __restrict__ zpage)
{
    __shared__ float sh[KK_];               // 16 KB, shared by both branches
    const int tid = threadIdx.x;
    const int b = blockIdx.x;

    if (b < 125) {
        float (*tile)[65] = (float(*)[65])sh;   // 32 x 65 (2080 fl used)
        const int v0 = b * 64;
        {   // read: 64 consecutive v per c-row (coalesced 256B)
            int vv = tid & 63, cc = tid >> 6;
            #pragma unroll
            for (int p = 0; p < 8; ++p)
                tile[cc + p * 4][vv] = x[(cc + p * 4) * V_ + v0 + vv];
        }
        __syncthreads();
        {   // write xt (coalesced 128B rows)
            int c = tid & 31, vl = tid >> 5;
            #pragma unroll
            for (int p = 0; p < 8; ++p) {
                int v = vl + p * 8;
                xt[(v0 + v) * 32 + c] = f2h(tile[c][v]);
            }
        }
        return;
    }

    int nb = b - 125;
    if (nb < NP_) {
        const bool live = nb < OC_;
        for (int i = tid; i < KK_; i += 256)
            sh[i] = live ? w_off[(size_t)nb * KK_ + i] : 0.f;
        __syncthreads();
        for (int j = tid; j < KK_; j += 256) {
            int tap = j >> 5, c = j & 31;
            Bprep[(size_t)nb * KK_ + j] = f2h(sh[c * K3_ + tap]);
        }
        return;
    }

    int j = (nb - NP_) * 256 + tid;
    if (j < 4000)  { wdwT[j] = w_dw[(j & 31) * K3_ + (j >> 5)]; return; }
    j -= 4000;
    if (j < 10976) { wspT[j] = w_sp[(j & 31) * 343 + (j >> 5)]; return; }
    j -= 10976;
    if (j < 1024)  { wpwT[j] = w_pw[(j & 31) * 32 + (j >> 5)]; return; }
    j -= 1024;
    if (j < 16)    { zpage[j] = 0.f; return; }
}

// ---------------------------------------------------------------------------
// Offset conv as implicit-GEMM MFMA (f16): D[8000][384] = A[8000][4000]*B.
// EXACT R4 STRUCTURE (verified best: ~54-56us, conflicts=0). Tile 64x64,
// BK=64 (2 taps/iter), 4 waves 2x2, wave tile 32x32. 2-phase pipeline,
// global_load_lds staging, double-buffered LDS (32KB), one barrier/K-step.
// LDS XOR-swizzle (T2, both-sides): write side fetches inverse-swizzled
// global chunk (linear LDS dest); read side XORs quad with (lrow>>1)&3.
// Ledger (R5-R8): 128-tile, counted-vmcnt 4-buf, B-in-VGPR, cube scheme
// all regressed (occupancy / barrier-drain / bank-uniformity). Keep R4.
// Writes offbT[v][n] f16 (+bias).
// ---------------------------------------------------------------------------
__global__ __launch_bounds__(256) void gemm_off_kernel(
    const unsigned short* __restrict__ xt,
    const unsigned short* __restrict__ Bprep,
    const float* __restrict__ b_off,
    const float* __restrict__ zpage,
    unsigned short* __restrict__ offbT)
{
    __shared__ unsigned short A_lds[2][2][64 * 32];   // [buf][h][row*32+k]
    __shared__ unsigned short B_lds[2][2][64 * 32];

    const int t    = threadIdx.x;
    const int lane = t & 63;
    const int wave = t >> 6;
    const int wr   = wave >> 1;
    const int wc   = wave & 1;
    const int quad = lane >> 4;
    const int lrow = lane & 15;
    const int M0   = blockIdx.x * 64;
    const int N0   = blockIdx.y * 64;

    const int srow = t >> 2;
    const int soff = ((t & 3) ^ ((t >> 3) & 3)) * 8;   // shorts, swizzled
    const int mg = M0 + srow;
    const int az = mg / 400, arm = mg % 400;
    const int ay = arm / 20, ax = arm % 20;
    const unsigned short* brow = Bprep + (size_t)(N0 + srow) * KK_;
    const unsigned short* zp   = (const unsigned short*)zpage;
    const int ldsoff = wave * 512;          // shorts: wave's 1024B chunk
    const int xorc = (lrow >> 1) & 3;

    f32x4 acc[2][2] = {};

    auto stage = [&](int buf, int tap0) {
        #pragma unroll
        for (int h = 0; h < 2; ++h) {
            int tap = tap0 + h;
            int kz = tap / 25, ky = (tap / 5) % 5, kx = tap % 5;
            int zi = az - 2 + kz, yi = ay - 2 + ky, xi = ax - 2 + kx;
            bool intap = tap < K3_;
            bool ok = intap & ((unsigned)zi < (unsigned)S_)
                            & ((unsigned)yi < (unsigned)S_)
                            & ((unsigned)xi < (unsigned)S_);
            int px = zi * 400 + yi * 20 + xi;
            const unsigned short* ga = ok    ? (xt + px * 32 + soff)    : zp;
            const unsigned short* gb = intap ? (brow + tap * 32 + soff) : zp;
            __builtin_amdgcn_global_load_lds(
                (const __attribute__((address_space(1))) void*)ga,
                (__attribute__((address_space(3))) void*)(&A_lds[buf][h][ldsoff]),
                16, 0, 0);
            __builtin_amdgcn_global_load_lds(
                (const __attribute__((address_space(1))) void*)gb,
                (__attribute__((address_space(3))) void*)(&B_lds[buf][h][ldsoff]),
                16, 0, 0);
        }
    };

    stage(0, 0);
    __syncthreads();

    int cur = 0;
    for (int it = 0; it < 63; ++it) {
        if (it < 62) stage(cur ^ 1, (it + 1) * 2);
        #pragma unroll
        for (int h = 0; h < 2; ++h) {
            bf16x8 af[2], bf[2];
            #pragma unroll
            for (int mi = 0; mi < 2; ++mi)
                af[mi] = *(const bf16x8*)&A_lds[cur][h][(wr * 32 + mi * 16 + lrow) * 32 + (quad ^ xorc) * 8];
            #pragma unroll
            for (int ni = 0; ni < 2; ++ni)
                bf[ni] = *(const bf16x8*)&B_lds[cur][h][(wc * 32 + ni * 16 + lrow) * 32 + (quad ^ xorc) * 8];
            #pragma unroll
            for (int mi = 0; mi < 2; ++mi)
                #pragma unroll
                for (int ni = 0; ni < 2; ++ni)
                    acc[mi][ni] = __builtin_amdgcn_mfma_f32_16x16x32_f16(
                        af[mi], bf[ni], acc[mi][ni], 0, 0, 0);
        }
        __syncthreads();
        cur ^= 1;
    }

    #pragma unroll
    for (int mi = 0; mi < 2; ++mi) {
        #pragma unroll
        for (int ni = 0; ni < 2; ++ni) {
            int n = N0 + wc * 32 + ni * 16 + lrow;
            if (n < OC_) {
                float bias = b_off[n];
                #pragma unroll
                for (int r = 0; r < 4; ++r) {
                    int row = wr * 32 + mi * 16 + quad * 4 + r;
                    offbT[(size_t)(M0 + row) * 384 + n] = f2h(acc[mi][ni][r] + bias);
                }
            }
        }
    }
}

// ---------------------------------------------------------------------------
// xp[v][c] = half2(x[v][c], x[v+1][c]) — makes the (w0,w1) trilinear x-pair
// a single dword load in deform. xp[7999].y = 0 (never used with nonzero wt).
// MUST run after gemm: xp aliases Bprep (R13 erratum — no pre-gemm space).
// ---------------------------------------------------------------------------
__global__ __launch_bounds__(256) void pack_xp_kernel(
    const unsigned short* __restrict__ xt, unsigned* __restrict__ xp)
{
    int i = blockIdx.x * 256 + threadIdx.x;
    if (i >= 256000) return;
    unsigned lo = xt[i];
    unsigned hi = (i < 256000 - 32) ? (unsigned)xt[i + 32] : 0u;
    xp[i] = lo | (hi << 16);
}

// ---------------------------------------------------------------------------
// Deformable depthwise sample, two-phase. EXACT R18 FORM (verified best,
// 173.6us e2e). R19's TLP-split (VB 4, parity-g reduction) REGRESSED +4.7us
// — per-block fixed costs doubled, occupancy reading was scheduler stagger
// not a residency cap. MLP ladder final: tap unroll 16.
// Phase 1: per (voxel, tap) geometry -> 4 packed half2 weights (trilinear
//          factors pre-multiplied) + 4 final gather indices. 32B/entry.
// Phase 2: thread=(v,c); 2 broadcast LDS reads, 4 dword gathers, 4 fdot2.
// ---------------------------------------------------------------------------
#define VB 8
__global__ __launch_bounds__(256) void deform_kernel(
    const unsigned* __restrict__ xp,
    const float* __restrict__ wdwT,
    const float* __restrict__ b_dw,
    const unsigned short* __restrict__ offbT,
    float* __restrict__ attn1T)
{
    __shared__ unsigned sw[VB * 128 * 8];   // 32 KB, 32B per (v,tap) entry
    const int tid = threadIdx.x;
    const int Vb = blockIdx.x * VB;

    for (int idx = tid; idx < VB * 128; idx += 256) {
        int vl = idx >> 7, tap = idx & 127;
        if (tap < K3_) {
            int v = Vb + vl;
            int z = v / 400, rm = v % 400;
            int y = rm / 20, xx = rm % 20;
            int kz = tap / 25, ky = (tap / 5) % 5, kx = tap % 5;
            const unsigned short* ob = offbT + v * 384 + 3 * tap;
            float pd = (float)(z - 2 + kz) + h2f(ob[0]);
            float ph = (float)(y - 2 + ky) + h2f(ob[1]);
            float pw = (float)(xx - 2 + kx) + h2f(ob[2]);
            float fd0 = floorf(pd), fh0 = floorf(ph), fw0 = floorf(pw);
            float fd = pd - fd0, fh = ph - fh0, fw = pw - fw0;
            int id = (int)fd0, ih = (int)fh0, iw = (int)fw0;
            int d0 = min(max(id, 0), S_ - 1), d1 = min(max(id + 1, 0), S_ - 1);
            int h0 = min(max(ih, 0), S_ - 1), h1 = min(max(ih + 1, 0), S_ - 1);
            float wd0 = ((unsigned)id       < (unsigned)S_) ? 1.f - fd : 0.f;
            float wd1 = ((unsigned)(id + 1) < (unsigned)S_) ? fd       : 0.f;
            float wh0 = ((unsigned)ih       < (unsigned)S_) ? 1.f - fh : 0.f;
            float wh1 = ((unsigned)(ih + 1) < (unsigned)S_) ? fh       : 0.f;
            float ww0 = ((unsigned)iw       < (unsigned)S_) ? 1.f - fw : 0.f;
            float ww1 = ((unsigned)(iw + 1) < (unsigned)S_) ? fw       : 0.f;
            // x-pair via xp[p] = (x[p], x[p+1]); iw<0 handled by weight swap.
            int px; float wwa, wwb;
            if (iw < 0) { px = 0;             wwa = ww1; wwb = 0.f; }
            else        { px = min(iw, S_-1); wwa = ww0; wwb = ww1; }
            int r00 = d0 * 400 + h0 * 20 + px;
            int r01 = d0 * 400 + h1 * 20 + px;
            int r10 = d1 * 400 + h0 * 20 + px;
            int r11 = d1 * 400 + h1 * 20 + px;
            float w00 = wd0 * wh0, w01 = wd0 * wh1;
            float w10 = wd1 * wh0, w11 = wd1 * wh1;
            unsigned* q = &sw[idx * 8];
            q[0] = pkh2(w00 * wwa, w00 * wwb);
            q[1] = pkh2(w01 * wwa, w01 * wwb);
            q[2] = pkh2(w10 * wwa, w10 * wwb);
            q[3] = pkh2(w11 * wwa, w11 * wwb);
            q[4] = (unsigned)r00 | ((unsigned)r01 << 16);
            q[5] = (unsigned)r10 | ((unsigned)r11 << 16);
        }
    }
    __syncthreads();

    const int c = tid & 31;
    const int vl = tid >> 5;
    const int v = Vb + vl;
    const unsigned* xpc = xp + c;
    float acc = 0.f;
    #pragma unroll 16
    for (int tap = 0; tap < K3_; ++tap) {
        const unsigned* q = &sw[(vl * 128 + tap) * 8];
        unsigned w00u = q[0], w01u = q[1], w10u = q[2], w11u = q[3];
        unsigned pA = q[4], pB = q[5];
        int p00 = pA & 0xFFFFu, p01 = pA >> 16;
        int p10 = pB & 0xFFFFu, p11 = pB >> 16;
        float s = dot2(xpc[p00 * 32], w00u,
                  dot2(xpc[p01 * 32], w01u,
                  dot2(xpc[p10 * 32], w10u,
                  dot2(xpc[p11 * 32], w11u, 0.f))));
        acc += wdwT[tap * 32 + c] * s;
    }
    attn1T[v * 32 + c] = acc + b_dw[c];
}

// ---------------------------------------------------------------------------
// FUSED: depthwise 7^3 conv (dil 3, pad 9) + pointwise 32x32 + gate.
// EXACT R18 FORM (verified best). HYBRID bounds: runtime kz/ky bounds skip
// ~45% of (kz,ky) pairs, NO divergence; inner kx FULLY UNROLLED (7-deep
// MLP); ky unroll 2 (R16), kz unroll 2 (R18).
// Phase A: thread (vl,c) computes spatial value -> s_attn[vl][c] (1 KB LDS).
// Phase B: thread (vl,o=c): out[o][v] = x[o][v] *
//          (b_pw[o] + sum_c wpwT[c][o]*s_attn[vl][c]); LDS reads broadcast.
// ---------------------------------------------------------------------------
__global__ __launch_bounds__(256) void spatial_pw_kernel(
    const float* __restrict__ wspT,
    const float* __restrict__ b_sp,
    const float* __restrict__ attn1T,
    const float* __restrict__ wpwT,
    const float* __restrict__ b_pw,
    const float* __restrict__ x,
    float* __restrict__ out)
{
    __shared__ float s_attn[8][32];
    int t = threadIdx.x;
    int c = t & 31;
    int vl = t >> 5;
    int v = blockIdx.x * 8 + vl;
    int z = v / 400, rm = v % 400;
    int y = rm / 20, xx = rm % 20;

    // Valid ranges: 0 <= q-9+3k <= 19 -> ceil((9-q)/3) <= k <= (28-q)/3.
    int kz_lo = max(0, (11 - z) / 3), kz_hi = min(6, (28 - z) / 3);
    int ky_lo = max(0, (11 - y) / 3), ky_hi = min(6, (28 - y) / 3);

    float acc = 0.f;
    #pragma unroll 2
    for (int kz = kz_lo; kz <= kz_hi; ++kz) {
        int zi = z - 9 + 3 * kz;                 // always in-bounds
        #pragma unroll 2
        for (int ky = ky_lo; ky <= ky_hi; ++ky) {
            int yi = y - 9 + 3 * ky;             // always in-bounds
            int abase = (zi * 400 + yi * 20) * 32 + c;
            int wbase = (kz * 49 + ky * 7) * 32 + c;
            #pragma unroll
            for (int kx = 0; kx < 7; ++kx) {     // full unroll: 7-deep MLP
                int xi = xx - 9 + 3 * kx;
                bool xv = (unsigned)xi < (unsigned)S_;
                int xc2 = min(max(xi, 0), S_ - 1);
                float a = attn1T[abase + xc2 * 32];
                float w = wspT[wbase + kx * 32];
                acc += xv ? a * w : 0.f;
            }
        }
    }
    s_attn[vl][c] = acc + b_sp[c];
    __syncthreads();

    const int o = c;
    float acc2 = b_pw[o];
    #pragma unroll
    for (int cc = 0; cc < C_; ++cc)
        acc2 += wpwT[cc * 32 + o] * s_attn[vl][cc];
    out[o * V_ + v] = x[o * V_ + v] * acc2;
}

// ---------------------------------------------------------------------------
extern "C" void kernel_launch(void* const* d_in, const int* in_sizes, int n_in,
                              void* d_out, int out_size, void* d_ws, size_t ws_size,
                              hipStream_t stream)
{
    const float* x     = (const float*)d_in[0];
    const float* w_off = (const float*)d_in[1];
    const float* b_off = (const float*)d_in[2];
    const float* w_dw  = (const float*)d_in[3];
    const float* b_dw  = (const float*)d_in[4];
    const float* w_sp  = (const float*)d_in[5];
    const float* b_sp  = (const float*)d_in[6];
    const float* w_pw  = (const float*)d_in[7];
    const float* b_pw  = (const float*)d_in[8];
    float* ws = (float*)d_ws;
    float* out = (float*)d_out;

    unsigned short* xt    = (unsigned short*)(ws + WS_XT);
    unsigned short* offbT = (unsigned short*)(ws + WS_OFFB);
    unsigned short* Bprep = (unsigned short*)(ws + WS_BPREP);
    unsigned*       xp    = (unsigned*)(ws + WS_XP);

    // 125 tile blocks + 384 prep_b rows + 63 weight-tail blocks = 572
    hipLaunchKernelGGL(prep_kernel, dim3(572), dim3(256), 0, stream,
                       x, w_off, w_dw, w_sp, w_pw,
                       xt, Bprep,
                       ws + WS_WDWT, ws + WS_WSPT, ws + WS_WPWT, ws + WS_ZERO);

    hipLaunchKernelGGL(gemm_off_kernel, dim3(125, 6), dim3(256), 0, stream,
                       xt, Bprep, b_off, ws + WS_ZERO, offbT);

    hipLaunchKernelGGL(pack_xp_kernel, dim3(1000), dim3(256), 0, stream,
                       xt, xp);

    hipLaunchKernelGGL(deform_kernel, dim3(1000), dim3(256), 0, stream,
                       xp, ws + WS_WDWT, b_dw, offbT, ws + WS_ATTN1T);

    hipLaunchKernelGGL(spatial_pw_kernel, dim3(1000), dim3(256), 0, stream,
                       ws + WS_WSPT, b_sp, ws + WS_ATTN1T,
                       ws + WS_WPWT, b_pw, x, out);
}